// Round 7
// baseline (167.506 us; speedup 1.0000x reference)
//
#include <hip/hip_runtime.h>

typedef _Float16 f16;
typedef _Float16 f16x2 __attribute__((ext_vector_type(2)));
typedef _Float16 f16x4 __attribute__((ext_vector_type(4)));
typedef _Float16 f16x8 __attribute__((ext_vector_type(8)));
typedef float    f32x4 __attribute__((ext_vector_type(4)));

#define NB   8
#define TE   2048
#define TD   2048
#define DIM  256
#define NBTD (NB * TD)
#define LOG2E 1.44269504088896340736f

#define AS1(p) ((const __attribute__((address_space(1))) void*)(p))
#define AS3(p) ((__attribute__((address_space(3))) void*)(p))
#define MFMA16(a,b,c) __builtin_amdgcn_mfma_f32_16x16x32_f16((a),(b),(c),0,0,0)
#define SHUF8(x,y) __builtin_shufflevector((x),(y),0,1,2,3,4,5,6,7)

__device__ __forceinline__ unsigned lds_u32(void* p) {
    return (unsigned)(size_t)((__attribute__((address_space(3))) void*)p);
}
// ds_read_b64_tr_b16 (validated r4-r6): per-lane 8B payload fetch at its own addr
// (base + (l&15)*8 within a contiguous 128B 4x16 row-major block), fixed in-group
// crossbar delivers out[l][j] = block[row j][col l&15].
#define TR_RD(dst, a, OFFS) \
    asm volatile("ds_read_b64_tr_b16 %0, %1 offset:" OFFS : "=v"(dst) : "v"(a))

// ---------------- prep: enc fp32 -> f16, same layout ----------------
__global__ __launch_bounds__(256) void prep_kernel(const float* __restrict__ enc,
                                                   f16* __restrict__ ench) {
    size_t i = ((size_t)blockIdx.x * 256 + threadIdx.x) * 8;
    float4 v0 = *(const float4*)(enc + i);
    float4 v1 = *(const float4*)(enc + i + 4);
    f16x8 o;
    o[0]=(f16)v0.x; o[1]=(f16)v0.y; o[2]=(f16)v0.z; o[3]=(f16)v0.w;
    o[4]=(f16)v1.x; o[5]=(f16)v1.y; o[6]=(f16)v1.z; o[7]=(f16)v1.w;
    *(f16x8*)(ench + i) = o;
}

// ---------------- fused attention: mega-tile e64 x t32, role-split 4 waves ----------------
// Wave w: QK e-slice [16w,16w+16) x t32 (A-reads 8KB/iter, not the full tile) and
// PV d-slice [64w,64w+64) x t32 (tr-reads 8KB/iter). Per iter covers t32 x e64 = 2048
// (t,e) cells at ~10.5 B LDS traffic per cell (r6: 66 B) -- amortizes fences/barriers 4x.
// Cross-wave rowmax via 512B exchange (float4/row); P shared [t32][e64] f16, pitch 128B,
// octet-swizzled: octet o of row t placed at (o ^ (t&7))*16 (write & read verified inverse).
// NAT tile 64e x 256d subtiled (proven): byte(e,d) = ((e>>2)*16+(d>>4))*128+(e&3)*32+(d&15)*2.
// Schedule/iter: QK -> bar1 -> [stage(it+1) | max-merge, exp, P-write, l] -> bar2 ->
// PV (2 batched fences) -> bar3 (drains stage, protects NAT for next QK).
// LDS 70,144 B -> 2 blocks/CU; ~140 VGPR (cap 256 at 2 waves/EU) -> no spill risk.
#define NATSZ  32768
#define LDS_P  65536
#define LDS_X  69632

__global__ __launch_bounds__(256, 2) void attn_kernel(
        const float* __restrict__ dec32,
        const f16*  __restrict__ enc_h,
        f16*   __restrict__ ctxp,
        f16x2* __restrict__ ml,
        float* __restrict__ out) {
    __shared__ __align__(16) char lds[70144];
    const int tid  = threadIdx.x;
    const int lane = tid & 63;
    const int w    = tid >> 6;    // wave: QK e-slice AND PV d-slice index
    const int tcol = lane & 15;
    const int q    = lane >> 4;

    const int b  = blockIdx.x;            // XCD pin: fid%8 = b
    const int t0 = blockIdx.y * 32;
    const int z  = blockIdx.z;            // split 0/1
    const int tile0 = z * 16;             // e64-tiles
    const int ITERS = 16;

    const char* encb = (const char*)(enc_h + (size_t)b * TE * DIM);

    // staging inverse map: chunk c = i*256+tid (16B); e = e0+8i, d i-independent
    const int e0s = ((tid >> 7) << 2) | ((tid >> 1) & 3);
    const int dss = (((tid >> 3) & 15) << 4) | ((tid & 1) << 3);
    const int sgo = e0s * 512 + dss * 2;
    char* sdst = lds + tid * 16;

    // QK A base: e = 16w + tcol, k-octet ks*32+q*8 -> qkb + ks*256 (+nat)
    const int qkb = (4 * w + (tcol >> 2)) * 2048 + (q >> 1) * 128
                  + (tcol & 3) * 32 + (q & 1) * 16;
    // P write base: t row = tcol (+tn*2048); octet o = 2w+(q>>1) at (o^(t&7))*16, half (q&1)*8
    const int pwo  = LDS_P + tcol * 128 + (((w * 2 + (q >> 1)) ^ (tcol & 7)) << 4)
                   + ((q & 1) << 3);
    // pf read base: octet o = eks*4+q -> bits01 q^(tcol&3), bit2 eks^((tcol>>2)&1)
    const int pf0o = LDS_P + tcol * 128 + ((q ^ (tcol & 3)) << 4)
                   + (((tcol >> 2) & 1) << 6);
    const int pf1o = pf0o ^ 64;
    // tr base: block (E = eks*8+2q (+p), D = 4w+dd) at (E*16+D)*128, chunk tcol*8
    const unsigned TRB = lds_u32(lds) + (unsigned)(q * 4096 + w * 512 + tcol * 8);

    // Q fragments: B[k=ks*32+q*8+j][n=t], t = t0 + tn*16 + tcol (64 VGPR)
    f16x8 qf[2][8];
    {
        const float* qrow = dec32 + ((size_t)b * TD + t0 + tcol) * DIM + q * 8;
        #pragma unroll
        for (int tn = 0; tn < 2; tn++)
            #pragma unroll
            for (int ks = 0; ks < 8; ks++) {
                const float* p = qrow + (size_t)tn * 16 * DIM + ks * 32;
                float4 u0 = *(const float4*)(p);
                float4 v0 = *(const float4*)(p + 4);
                f16x8 o;
                o[0]=(f16)u0.x; o[1]=(f16)u0.y; o[2]=(f16)u0.z; o[3]=(f16)u0.w;
                o[4]=(f16)v0.x; o[5]=(f16)v0.y; o[6]=(f16)v0.z; o[7]=(f16)v0.w;
                qf[tn][ks] = o;
            }
    }

    { // stage tile0 -> buf0 (32KB, 8 x 16B per thread)
        const char* s = encb + (size_t)tile0 * 32768 + sgo;
        #pragma unroll
        for (int i = 0; i < 8; i++)
            __builtin_amdgcn_global_load_lds(AS1(s + i * 4096), AS3(sdst + i * 4096), 16, 0, 0);
    }

    const f32x4 zero4 = {0.f, 0.f, 0.f, 0.f};
    float m_[2] = {-INFINITY, -INFINITY};
    float l_[2] = {0.f, 0.f};
    f32x4 ctx[4][2];
    #pragma unroll
    for (int dd = 0; dd < 4; dd++) { ctx[dd][0] = zero4; ctx[dd][1] = zero4; }

    __syncthreads();   // tile0 staged & drained

    for (int it = 0; it < ITERS; ++it) {
        const int nat = (it & 1) << 15;
        // ---- QK: St[e16-slice][t32] ----
        f32x4 st[2] = {zero4, zero4};
        const char* natp = lds + nat + qkb;
        #pragma unroll
        for (int ks = 0; ks < 8; ks++) {
            f16x8 af = *(const f16x8*)(natp + ks * 256);
            st[0] = MFMA16(af, qf[0][ks], st[0]);
            st[1] = MFMA16(af, qf[1][ks], st[1]);
        }
        #pragma unroll
        for (int tn = 0; tn < 2; tn++) {
            float m0 = fmaxf(fmaxf(st[tn][0], st[tn][1]), fmaxf(st[tn][2], st[tn][3]));
            m0 = fmaxf(m0, __shfl_xor(m0, 16, 64));
            m0 = fmaxf(m0, __shfl_xor(m0, 32, 64));
            if (q == 0) *(float*)(lds + LDS_X + (tn * 16 + tcol) * 16 + w * 4) = m0;
        }
        __syncthreads();   // bar1: slice maxes visible
        // stage next tile (buffer's prior readers done before bar3(it-1) < bar1(it));
        // drained at bar3(it) before QK(it+1) reads it.
        if (it + 1 < ITERS) {
            const char* s = encb + (size_t)(tile0 + it + 1) * 32768 + sgo;
            char* dd2 = lds + (((it + 1) & 1) << 15) + tid * 16;
            #pragma unroll
            for (int i = 0; i < 8; i++)
                __builtin_amdgcn_global_load_lds(AS1(s + i * 4096), AS3(dd2 + i * 4096), 16, 0, 0);
        }
        // ---- softmax merge + P publish + l ----
        bool bump = false;
        float al[2];
        #pragma unroll
        for (int tn = 0; tn < 2; tn++) {
            float4 m4 = *(const float4*)(lds + LDS_X + (tn * 16 + tcol) * 16);
            float mm = fmaxf(fmaxf(m4.x, m4.y), fmaxf(m4.z, m4.w));
            float ms = (float)(f16)fmaxf(m_[tn], mm);   // snap to f16 (proven r5/r6)
            al[tn] = __builtin_amdgcn_exp2f((m_[tn] - ms) * LOG2E);
            bump = bump || (ms > m_[tn]);
            m_[tn] = ms;
            f16x4 pv;
            float ssum = 0.f;
            #pragma unroll
            for (int r = 0; r < 4; r++) {               // e = 16w + q*4 + r
                float p = __builtin_amdgcn_exp2f((st[tn][r] - ms) * LOG2E);
                pv[r] = (f16)p;
                ssum += (float)pv[r];
            }
            *(f16x4*)(lds + pwo + tn * 2048) = pv;
            ssum += __shfl_xor(ssum, 16, 64);
            ssum += __shfl_xor(ssum, 32, 64);
            l_[tn] = l_[tn] * al[tn] + ssum;            // this wave's e16-slice partial
        }
        if (__any(bump)) {
            #pragma unroll
            for (int dd = 0; dd < 4; dd++)
                #pragma unroll
                for (int tn = 0; tn < 2; tn++) {
                    ctx[dd][tn][0] *= al[tn]; ctx[dd][tn][1] *= al[tn];
                    ctx[dd][tn][2] *= al[tn]; ctx[dd][tn][3] *= al[tn];
                }
        }
        __syncthreads();   // bar2: P visible to all waves
        // ---- PV: ctx[d64-slice][t32]; one batched fence per e32-half ----
        const unsigned trv = TRB + (unsigned)nat;
        {   // eks = 0: e 0..31
            f16x8 pfA = *(const f16x8*)(lds + pf0o);
            f16x8 pfB = *(const f16x8*)(lds + pf0o + 2048);
            f16x4 t00,t01,t10,t11,t20,t21,t30,t31;
            TR_RD(t00, trv, "0");    TR_RD(t01, trv, "2048");
            TR_RD(t10, trv, "128");  TR_RD(t11, trv, "2176");
            TR_RD(t20, trv, "256");  TR_RD(t21, trv, "2304");
            TR_RD(t30, trv, "384");  TR_RD(t31, trv, "2432");
            asm volatile("s_waitcnt lgkmcnt(0)" ::: "memory");
            __builtin_amdgcn_sched_barrier(0);
            f16x8 a0 = SHUF8(t00,t01), a1 = SHUF8(t10,t11);
            f16x8 a2 = SHUF8(t20,t21), a3 = SHUF8(t30,t31);
            ctx[0][0] = MFMA16(a0, pfA, ctx[0][0]); ctx[0][1] = MFMA16(a0, pfB, ctx[0][1]);
            ctx[1][0] = MFMA16(a1, pfA, ctx[1][0]); ctx[1][1] = MFMA16(a1, pfB, ctx[1][1]);
            ctx[2][0] = MFMA16(a2, pfA, ctx[2][0]); ctx[2][1] = MFMA16(a2, pfB, ctx[2][1]);
            ctx[3][0] = MFMA16(a3, pfA, ctx[3][0]); ctx[3][1] = MFMA16(a3, pfB, ctx[3][1]);
        }
        {   // eks = 1: e 32..63 (E += 8 -> offset +16384)
            f16x8 pfA = *(const f16x8*)(lds + pf1o);
            f16x8 pfB = *(const f16x8*)(lds + pf1o + 2048);
            f16x4 t00,t01,t10,t11,t20,t21,t30,t31;
            TR_RD(t00, trv, "16384"); TR_RD(t01, trv, "18432");
            TR_RD(t10, trv, "16512"); TR_RD(t11, trv, "18560");
            TR_RD(t20, trv, "16640"); TR_RD(t21, trv, "18688");
            TR_RD(t30, trv, "16768"); TR_RD(t31, trv, "18816");
            asm volatile("s_waitcnt lgkmcnt(0)" ::: "memory");
            __builtin_amdgcn_sched_barrier(0);
            f16x8 a0 = SHUF8(t00,t01), a1 = SHUF8(t10,t11);
            f16x8 a2 = SHUF8(t20,t21), a3 = SHUF8(t30,t31);
            ctx[0][0] = MFMA16(a0, pfA, ctx[0][0]); ctx[0][1] = MFMA16(a0, pfB, ctx[0][1]);
            ctx[1][0] = MFMA16(a1, pfA, ctx[1][0]); ctx[1][1] = MFMA16(a1, pfB, ctx[1][1]);
            ctx[2][0] = MFMA16(a2, pfA, ctx[2][0]); ctx[2][1] = MFMA16(a2, pfB, ctx[2][1]);
            ctx[3][0] = MFMA16(a3, pfA, ctx[3][0]); ctx[3][1] = MFMA16(a3, pfB, ctx[3][1]);
        }
        __syncthreads();   // bar3: stage(it+1) drained; NAT safe for next QK
    }

    // ---- epilogue: sum l partials across 4 waves, write normalized slice ----
    if (q == 0) {
        *(float*)(lds + LDS_X + tcol * 16 + w * 4)        = l_[0];
        *(float*)(lds + LDS_X + (16 + tcol) * 16 + w * 4) = l_[1];
    }
    __syncthreads();
    float L[2], inv[2];
    #pragma unroll
    for (int tn = 0; tn < 2; tn++) {
        float4 l4 = *(const float4*)(lds + LDS_X + (tn * 16 + tcol) * 16);
        L[tn]   = (l4.x + l4.y) + (l4.z + l4.w);
        inv[tn] = 1.0f / L[tn];
    }
    const size_t row = (size_t)b * TD + t0 + tcol;
    if (z == 0) {
        f16* cb = ctxp + row * DIM + w * 64;
        #pragma unroll
        for (int tn = 0; tn < 2; tn++)
            #pragma unroll
            for (int dd = 0; dd < 4; dd++) {
                f16x4 cv;
                #pragma unroll
                for (int r = 0; r < 4; r++) cv[r] = (f16)(ctx[dd][tn][r] * inv[tn]);
                *(f16x4*)(cb + (size_t)tn * 16 * DIM + dd * 16 + q * 4) = cv;
            }
    } else {
        float* ob = out + row * 512 + 256 + w * 64;   // park f32 partial in ctx area
        #pragma unroll
        for (int tn = 0; tn < 2; tn++)
            #pragma unroll
            for (int dd = 0; dd < 4; dd++) {
                float4 cv;
                cv.x = ctx[dd][tn][0] * inv[tn]; cv.y = ctx[dd][tn][1] * inv[tn];
                cv.z = ctx[dd][tn][2] * inv[tn]; cv.w = ctx[dd][tn][3] * inv[tn];
                *(float4*)(ob + (size_t)tn * 16 * 512 + dd * 16 + q * 4) = cv;
            }
    }
    if (w == 0 && q == 0) {
        #pragma unroll
        for (int tn = 0; tn < 2; tn++) {
            f16x2 v; v[0] = (f16)m_[tn]; v[1] = (f16)L[tn];   // m_ exactly f16 (snapped)
            ml[(size_t)z * NBTD + row + tn * 16] = v;
        }
    }
}

// ---------------- combine: merge 2 normalized partials + decoder passthrough ----------
__global__ __launch_bounds__(256) void combine_kernel(const float* __restrict__ dec32,
        const f16* __restrict__ ctxp, const f16x2* __restrict__ ml,
        float* __restrict__ out) {
    int idx  = blockIdx.x * 256 + threadIdx.x;
    int trow = idx >> 5;              // b*TD + t
    int dg   = (idx & 31) * 8;
    f16x2 v0 = ml[trow];
    f16x2 v1 = ml[(size_t)NBTD + trow];
    float m0 = (float)v0[0], l0 = (float)v0[1];
    float m1 = (float)v1[0], l1 = (float)v1[1];
    float M  = fmaxf(m0, m1);
    float w0 = __builtin_amdgcn_exp2f((m0 - M) * LOG2E) * l0;
    float w1 = __builtin_amdgcn_exp2f((m1 - M) * LOG2E) * l1;
    float invL = 1.0f / (w0 + w1);
    w0 *= invL; w1 *= invL;
    float acc[8];
    {   // split 0: f16 partial in ctxp
        f16x8 v = *(const f16x8*)(ctxp + (size_t)trow * DIM + dg);
        #pragma unroll
        for (int j = 0; j < 8; j++) acc[j] = w0 * (float)v[j];
    }
    {   // split 1: f32 partial parked in out's ctx area (read before overwrite)
        const float* o1 = out + (size_t)trow * 512 + 256 + dg;
        float4 p0 = *(const float4*)(o1);
        float4 p1 = *(const float4*)(o1 + 4);
        acc[0] += w1 * p0.x; acc[1] += w1 * p0.y; acc[2] += w1 * p0.z; acc[3] += w1 * p0.w;
        acc[4] += w1 * p1.x; acc[5] += w1 * p1.y; acc[6] += w1 * p1.z; acc[7] += w1 * p1.w;
    }
    float4 d0 = *(const float4*)(dec32 + (size_t)trow * DIM + dg);
    float4 d1 = *(const float4*)(dec32 + (size_t)trow * DIM + dg + 4);
    float* ob = out + (size_t)trow * 512;
    *(float4*)(ob + dg)     = d0;
    *(float4*)(ob + dg + 4) = d1;
    float4 c0, c1;
    c0.x=acc[0]; c0.y=acc[1]; c0.z=acc[2]; c0.w=acc[3];
    c1.x=acc[4]; c1.y=acc[5]; c1.z=acc[6]; c1.w=acc[7];
    *(float4*)(ob + 256 + dg)     = c0;
    *(float4*)(ob + 256 + dg + 4) = c1;
}

extern "C" void kernel_launch(void* const* d_in, const int* in_sizes, int n_in,
                              void* d_out, int out_size, void* d_ws, size_t ws_size,
                              hipStream_t stream) {
    (void)in_sizes; (void)n_in;
    const float* enc = (const float*)d_in[0];
    const float* dec = (const float*)d_in[1];
    float* out = (float*)d_out;

    const size_t MLB = (size_t)2 * NBTD * 4;          // 131,072 (f16x2 per split-row)
    const size_t HB  = (size_t)NB * TE * DIM * 2;     // 8,388,608 (ench)
    const size_t CSL = (size_t)NBTD * DIM * 2;        // 8,388,608 (split-0 f16 partial)
    const size_t NEED = MLB + HB + CSL;               // 16,908,288

    if (ws_size < NEED) {
        hipMemsetAsync(d_out, 0, (size_t)out_size * sizeof(float), stream);
        return;
    }
    f16x2* ml   = (f16x2*)d_ws;
    f16*   ench = (f16*)((char*)d_ws + MLB);
    f16*   ctxp = (f16*)((char*)d_ws + MLB + HB);

    prep_kernel<<<2048, 256, 0, stream>>>(enc, ench);
    attn_kernel<<<dim3(8, 64, 2), 256, 0, stream>>>(dec, ench, ctxp, ml, out);
    combine_kernel<<<2048, 256, 0, stream>>>(dec, ctxp, ml, out);
}